// Round 4
// baseline (657.112 us; speedup 1.0000x reference)
//
#include <hip/hip_runtime.h>
#include <hip/hip_bf16.h>
#include <cstdint>
#include <cstddef>

#define B_   128
#define NCH  64
#define T_   30720
#define TT   128          // time-steps per LDS tile (4 K-steps of 32)
#define EPSF 1e-12f
#define THRF 0.5f

typedef float  f32x4 __attribute__((ext_vector_type(4)));
typedef short  s16x8 __attribute__((ext_vector_type(8)));
typedef unsigned short u16;

static __device__ __forceinline__ short bf16s(float f) {
    return (short)__builtin_bit_cast(u16, __float2bfloat16(f));
}

// ---------------------------------------------------------------------------
// Stage 1: per (batch, T-chunk) block:
//   - stream x tile HBM -> LDS (bf16, RNE) + fused nontemporal copy to out_x
//   - MFMA Gram: P[b,c] = sum_t x x^T  (bf16 inputs; corr error <= ~4e-3,
//     40x below both the |corr|>=0.5 decision margin and the absmax threshold)
//   - S[b,c][n] = sum_t x[n][t]  (fp32, exact path for the mean correction)
// 256 threads = 4 waves; wave w owns rows w*16..w*16+15 (4 fragments 16x16).
// LDS [2 buf][64 ch][128 t] bf16, double-buffered, one barrier per tile.
// XOR swizzle at 16B granularity: byte_in_row ^= (ch&7)<<4  (2-way = free).
// ---------------------------------------------------------------------------
__global__ __launch_bounds__(256) void corr_stage1(
    const float* __restrict__ x, float* __restrict__ out_x,
    float* __restrict__ P, float* __restrict__ S,
    int split, int Tc)
{
    __shared__ __align__(16) u16 lds[2][NCH * TT];   // 2 x 16 KB

    const int tid  = threadIdx.x;
    const int lane = tid & 63;
    const int w    = tid >> 6;            // wave 0..3

    const int bid = blockIdx.x;
    const int b   = bid / split;
    const int c   = bid - b * split;

    const size_t base = (size_t)b * ((size_t)NCH * T_) + (size_t)c * Tc;
    const float* xb = x + base;
    float*       ob = out_x + base;

    // staging mapping: pass p covers channels p*16..p*16+15; each thread does
    // 8 consecutive floats at t = sg*8 (coalesced 64-lane rows).
    const int sch = tid >> 4;             // 0..15
    const int sg  = tid & 15;             // 0..15

    // MFMA fragment addressing
    const int r    = lane & 15;           // fragment row
    const int koff = (lane >> 4) << 4;    // byte offset of lane's 8 bf16 in K
    const int swz  = (r & 7) << 4;        // row XOR swizzle

    f32x4 acc[4];
    #pragma unroll
    for (int fn = 0; fn < 4; ++fn) acc[fn] = (f32x4)(0.f);
    float ssum[4] = {0.f, 0.f, 0.f, 0.f};

    const int ntile = Tc / TT;

    auto stage = [&](int tile, int buf) {
        const int tbase = tile * TT;
        #pragma unroll
        for (int p = 0; p < 4; ++p) {
            const int ch = p * 16 + sch;
            const size_t go = (size_t)ch * T_ + (size_t)(tbase + sg * 8);
            const f32x4 v0 = *reinterpret_cast<const f32x4*>(xb + go);
            const f32x4 v1 = *reinterpret_cast<const f32x4*>(xb + go + 4);
            __builtin_nontemporal_store(v0, reinterpret_cast<f32x4*>(ob + go));
            __builtin_nontemporal_store(v1, reinterpret_cast<f32x4*>(ob + go + 4));
            ssum[p] += ((v0.x + v0.y) + (v0.z + v0.w))
                     + ((v1.x + v1.y) + (v1.z + v1.w));
            s16x8 hv;
            hv[0] = bf16s(v0.x); hv[1] = bf16s(v0.y);
            hv[2] = bf16s(v0.z); hv[3] = bf16s(v0.w);
            hv[4] = bf16s(v1.x); hv[5] = bf16s(v1.y);
            hv[6] = bf16s(v1.z); hv[7] = bf16s(v1.w);
            const int ba = ch * (TT * 2) + ((sg * 16) ^ ((ch & 7) << 4));
            *reinterpret_cast<s16x8*>(reinterpret_cast<char*>(lds[buf]) + ba) = hv;
        }
    };

    stage(0, 0);
    __syncthreads();

    for (int t = 0; t < ntile; ++t) {
        if (t + 1 < ntile) stage(t + 1, (t + 1) & 1);   // issue-early prefetch
        const char* Lb = reinterpret_cast<const char*>(lds[t & 1]);
        #pragma unroll
        for (int ks = 0; ks < 4; ++ks) {
            const int tb = ((ks * 64 + koff) ^ swz);
            const s16x8 ah = *reinterpret_cast<const s16x8*>(
                Lb + (w * 16 + r) * (TT * 2) + tb);
            #pragma unroll
            for (int fn = 0; fn < 4; ++fn) {
                const s16x8 bh = *reinterpret_cast<const s16x8*>(
                    Lb + (fn * 16 + r) * (TT * 2) + tb);
                acc[fn] = __builtin_amdgcn_mfma_f32_16x16x32_bf16(ah, bh, acc[fn], 0, 0, 0);
            }
        }
        __syncthreads();
    }

    // ---- S reduction: ssum[p] belongs to channel p*16+sch, partial over sg ----
    float* sred = reinterpret_cast<float*>(lds[0]);   // 4 KB scratch
    #pragma unroll
    for (int p = 0; p < 4; ++p) sred[p * 256 + tid] = ssum[p];
    __syncthreads();
    if (tid < NCH) {
        const int pidx = tid >> 4, ridx = tid & 15;
        float s = 0.f;
        #pragma unroll
        for (int g = 0; g < 16; ++g) s += sred[pidx * 256 + ridx * 16 + g];
        S[(size_t)(b * split + c) * NCH + tid] = s;
    }

    // ---- P write: D layout col=lane&15, row=(lane>>4)*4+reg ----
    float* Pc = P + ((size_t)(b * split + c) << 12);
    const int rowc = w * 16 + ((lane >> 4) << 2);
    const int col  = lane & 15;
    #pragma unroll
    for (int fn = 0; fn < 4; ++fn)
        #pragma unroll
        for (int reg = 0; reg < 4; ++reg)
            Pc[(rowc + reg) * 64 + fn * 16 + col] = acc[fn][reg];
}

// ---------------------------------------------------------------------------
// Stage 2: combine chunk partials -> corr -> threshold -> adj
// ---------------------------------------------------------------------------
__global__ __launch_bounds__(256) void corr_stage2(
    const float* __restrict__ P, const float* __restrict__ S,
    float* __restrict__ adj, int split)
{
    const int idx = blockIdx.x * 256 + threadIdx.x;   // < 128*4096
    const int b  = idx >> 12;
    const int nm = idx & 4095;
    const int n  = nm >> 6;
    const int m  = nm & 63;

    float G = 0.f, Gnn = 0.f, Gmm = 0.f, Sn = 0.f, Sm = 0.f;
    for (int c = 0; c < split; ++c) {
        const float* Pc = P + ((size_t)(b * split + c) << 12);
        const float* Sc = S + (size_t)(b * split + c) * NCH;
        G   += Pc[nm];
        Gnn += Pc[n * 65];
        Gmm += Pc[m * 65];
        Sn  += Sc[n];
        Sm  += Sc[m];
    }
    const float invT = 1.0f / (float)T_;
    const float cov  = G   - Sn * Sm * invT;
    const float vn   = Gnn - Sn * Sn * invT;
    const float vm   = Gmm - Sm * Sm * invT;
    const float den  = sqrtf(vn) * sqrtf(vm) + EPSF;
    float corr = cov / den;
    if (n == m) corr = 0.f;
    adj[idx] = (fabsf(corr) >= THRF) ? corr : 0.f;
}

// ---------------------------------------------------------------------------
extern "C" void kernel_launch(void* const* d_in, const int* in_sizes, int n_in,
                              void* d_out, int out_size, void* d_ws, size_t ws_size,
                              hipStream_t stream)
{
    const float* x   = (const float*)d_in[0];
    float* out   = (float*)d_out;
    float* adj   = out;                                  // 128*64*64
    float* out_x = out + (size_t)B_ * NCH * NCH;         // passthrough x

    // workspace: P = [128*split][4096] f32, S = [128*split][64] f32
    int split = 16;
    while (split > 1 &&
           (size_t)B_ * split * (4096 + NCH) * sizeof(float) > ws_size)
        split >>= 1;

    float* P = (float*)d_ws;
    float* S = P + (size_t)B_ * split * 4096;
    const int Tc = T_ / split;

    corr_stage1<<<dim3(B_ * split), dim3(256), 0, stream>>>(x, out_x, P, S, split, Tc);
    corr_stage2<<<dim3((B_ * 4096) / 256), dim3(256), 0, stream>>>(P, S, adj, split);
}

// Round 5
// 514.665 us; speedup vs baseline: 1.2768x; 1.2768x over previous
//
#include <hip/hip_runtime.h>
#include <hip/hip_bf16.h>
#include <cstdint>
#include <cstddef>

#define B_   128
#define NCH  64
#define T_   30720
#define TT   128          // time-steps per LDS tile (4 K-steps of 32)
#define EPSF 1e-12f
#define THRF 0.5f

typedef float  f32x4 __attribute__((ext_vector_type(4)));
typedef short  s16x8 __attribute__((ext_vector_type(8)));
typedef unsigned short u16;

static __device__ __forceinline__ short bf16s(float f) {
    return (short)__builtin_bit_cast(u16, __float2bfloat16(f));
}

// ---------------------------------------------------------------------------
// Stage 1: per (batch, T-chunk) block:
//   - stream x tile HBM -> regs (issued one tile EARLY, in flight across the
//     MFMA phase) -> {nontemporal copy to out_x, bf16 cvt -> LDS} after the
//     barrier whose mandatory vmcnt-drain retires the loads for free (T14).
//   - MFMA Gram: P[b,c] = sum_t x x^T (bf16; corr error <= ~4e-3, 40x under
//     both the 0.5 decision margin and the 0.108 absmax threshold)
//   - S[b,c][n] = sum_t x[n][t] in fp32 (exact mean correction path)
// 256 threads = 4 waves; wave w owns output rows w*16..w*16+15 (4 frags).
// LDS [64 ch][128 t] bf16 single buffer, two barriers/tile (R3 schedule).
// XOR swizzle at 16B granularity: byte_in_row ^= (ch&7)<<4.
// ---------------------------------------------------------------------------
__global__ __launch_bounds__(256) void corr_stage1(
    const float* __restrict__ x, float* __restrict__ out_x,
    float* __restrict__ P, float* __restrict__ S,
    int split, int Tc)
{
    __shared__ __align__(16) u16 lds[NCH * TT];   // 16 KB

    const int tid  = threadIdx.x;
    const int lane = tid & 63;
    const int w    = tid >> 6;            // wave 0..3

    const int bid = blockIdx.x;
    const int b   = bid / split;
    const int c   = bid - b * split;

    const size_t base = (size_t)b * ((size_t)NCH * T_) + (size_t)c * Tc;
    const float* xb = x + base;
    float*       ob = out_x + base;

    // staging mapping: pass p covers channels p*16..p*16+15; each thread does
    // 8 consecutive floats at t = sg*8 (16 lanes x 32B = 512B coalesced rows).
    const int sch = tid >> 4;             // 0..15
    const int sg  = tid & 15;             // 0..15

    // MFMA fragment addressing
    const int r    = lane & 15;           // fragment row
    const int koff = (lane >> 4) << 4;    // byte offset of lane's 8 bf16 in K
    const int swz  = (r & 7) << 4;        // row XOR swizzle

    f32x4 acc[4];
    #pragma unroll
    for (int fn = 0; fn < 4; ++fn) acc[fn] = (f32x4)(0.f);
    float ssum[4] = {0.f, 0.f, 0.f, 0.f};

    const int ntile = Tc / TT;

    f32x4 R0[4], R1[4];                   // in-flight tile (32 VGPR)

    auto issue_loads = [&](int tile) {    // pure loads, nothing waits on them
        const int tbase = tile * TT;
        #pragma unroll
        for (int p = 0; p < 4; ++p) {
            const size_t go = (size_t)(p * 16 + sch) * T_ + (size_t)(tbase + sg * 8);
            R0[p] = *reinterpret_cast<const f32x4*>(xb + go);
            R1[p] = *reinterpret_cast<const f32x4*>(xb + go + 4);
        }
    };

    auto write_phase = [&](int tile) {    // NT copy-out + cvt + ds_write
        const int tbase = tile * TT;
        #pragma unroll
        for (int p = 0; p < 4; ++p) {
            const int ch = p * 16 + sch;
            const size_t go = (size_t)ch * T_ + (size_t)(tbase + sg * 8);
            __builtin_nontemporal_store(R0[p], reinterpret_cast<f32x4*>(ob + go));
            __builtin_nontemporal_store(R1[p], reinterpret_cast<f32x4*>(ob + go + 4));
            ssum[p] += ((R0[p].x + R0[p].y) + (R0[p].z + R0[p].w))
                     + ((R1[p].x + R1[p].y) + (R1[p].z + R1[p].w));
            s16x8 hv;
            hv[0] = bf16s(R0[p].x); hv[1] = bf16s(R0[p].y);
            hv[2] = bf16s(R0[p].z); hv[3] = bf16s(R0[p].w);
            hv[4] = bf16s(R1[p].x); hv[5] = bf16s(R1[p].y);
            hv[6] = bf16s(R1[p].z); hv[7] = bf16s(R1[p].w);
            const int ba = ch * (TT * 2) + ((sg * 16) ^ ((ch & 7) << 4));
            *reinterpret_cast<s16x8*>(reinterpret_cast<char*>(lds) + ba) = hv;
        }
    };

    issue_loads(0);
    write_phase(0);
    __syncthreads();

    for (int t = 0; t < ntile; ++t) {
        if (t + 1 < ntile) issue_loads(t + 1);   // in flight across compute
        const char* Lb = reinterpret_cast<const char*>(lds);
        #pragma unroll
        for (int ks = 0; ks < 4; ++ks) {
            const int tb = ((ks * 64 + koff) ^ swz);
            const s16x8 ah = *reinterpret_cast<const s16x8*>(
                Lb + (w * 16 + r) * (TT * 2) + tb);
            #pragma unroll
            for (int fn = 0; fn < 4; ++fn) {
                const s16x8 bh = *reinterpret_cast<const s16x8*>(
                    Lb + (fn * 16 + r) * (TT * 2) + tb);
                acc[fn] = __builtin_amdgcn_mfma_f32_16x16x32_bf16(ah, bh, acc[fn], 0, 0, 0);
            }
        }
        __syncthreads();                          // LDS reads done (drains vmcnt too)
        if (t + 1 < ntile) {
            write_phase(t + 1);                   // regs already retired by barrier
            __syncthreads();                      // writes visible before next compute
        }
    }

    // ---- S reduction: ssum[p] belongs to channel p*16+sch, partial over sg ----
    float* sred = reinterpret_cast<float*>(lds);   // 4 KB scratch
    #pragma unroll
    for (int p = 0; p < 4; ++p) sred[p * 256 + tid] = ssum[p];
    __syncthreads();
    if (tid < NCH) {
        const int pidx = tid >> 4, ridx = tid & 15;
        float s = 0.f;
        #pragma unroll
        for (int g = 0; g < 16; ++g) s += sred[pidx * 256 + ridx * 16 + g];
        S[(size_t)(b * split + c) * NCH + tid] = s;
    }

    // ---- P write: D layout col=lane&15, row=(lane>>4)*4+reg ----
    float* Pc = P + ((size_t)(b * split + c) << 12);
    const int rowc = w * 16 + ((lane >> 4) << 2);
    const int col  = lane & 15;
    #pragma unroll
    for (int fn = 0; fn < 4; ++fn)
        #pragma unroll
        for (int reg = 0; reg < 4; ++reg)
            Pc[(rowc + reg) * 64 + fn * 16 + col] = acc[fn][reg];
}

// ---------------------------------------------------------------------------
// Stage 2: combine chunk partials -> corr -> threshold -> adj
// ---------------------------------------------------------------------------
__global__ __launch_bounds__(256) void corr_stage2(
    const float* __restrict__ P, const float* __restrict__ S,
    float* __restrict__ adj, int split)
{
    const int idx = blockIdx.x * 256 + threadIdx.x;   // < 128*4096
    const int b  = idx >> 12;
    const int nm = idx & 4095;
    const int n  = nm >> 6;
    const int m  = nm & 63;

    float G = 0.f, Gnn = 0.f, Gmm = 0.f, Sn = 0.f, Sm = 0.f;
    for (int c = 0; c < split; ++c) {
        const float* Pc = P + ((size_t)(b * split + c) << 12);
        const float* Sc = S + (size_t)(b * split + c) * NCH;
        G   += Pc[nm];
        Gnn += Pc[n * 65];
        Gmm += Pc[m * 65];
        Sn  += Sc[n];
        Sm  += Sc[m];
    }
    const float invT = 1.0f / (float)T_;
    const float cov  = G   - Sn * Sm * invT;
    const float vn   = Gnn - Sn * Sn * invT;
    const float vm   = Gmm - Sm * Sm * invT;
    const float den  = sqrtf(vn) * sqrtf(vm) + EPSF;
    float corr = cov / den;
    if (n == m) corr = 0.f;
    adj[idx] = (fabsf(corr) >= THRF) ? corr : 0.f;
}

// ---------------------------------------------------------------------------
extern "C" void kernel_launch(void* const* d_in, const int* in_sizes, int n_in,
                              void* d_out, int out_size, void* d_ws, size_t ws_size,
                              hipStream_t stream)
{
    const float* x   = (const float*)d_in[0];
    float* out   = (float*)d_out;
    float* adj   = out;                                  // 128*64*64
    float* out_x = out + (size_t)B_ * NCH * NCH;         // passthrough x

    // workspace: P = [128*split][4096] f32, S = [128*split][64] f32
    int split = 8;
    while (split > 1 &&
           (size_t)B_ * split * (4096 + NCH) * sizeof(float) > ws_size)
        split >>= 1;

    float* P = (float*)d_ws;
    float* S = P + (size_t)B_ * split * 4096;
    const int Tc = T_ / split;

    corr_stage1<<<dim3(B_ * split), dim3(256), 0, stream>>>(x, out_x, P, S, split, Tc);
    corr_stage2<<<dim3((B_ * 4096) / 256), dim3(256), 0, stream>>>(P, S, adj, split);
}